// Round 9
// baseline (232.785 us; speedup 1.0000x reference)
//
#include <hip/hip_runtime.h>
#include <hip/hip_bf16.h>

namespace {
constexpr int B = 64, L = 1024, D = 64;
constexpr int KT = 256;        // k-window per block (1KB f32 rows -> contiguity)
constexpr int QS = 32;         // q per step
constexpr int NSTEP = L / QS;  // 32
constexpr int SP = 260;        // sbuf pitch (f32 words): 256 k + pad
constexpr int PP = 40;         // P^T pitch (bf16): 32 q + 8 pad, b128-aligned

typedef float f32x4 __attribute__((ext_vector_type(4)));
typedef int   i32x4 __attribute__((ext_vector_type(4)));
typedef __bf16 bf16x8 __attribute__((ext_vector_type(8)));

__device__ inline bf16x8 cvt8(const float* __restrict__ p) {
  f32x4 a = *reinterpret_cast<const f32x4*>(p);
  f32x4 b = *reinterpret_cast<const f32x4*>(p + 4);
  bf16x8 r;
  r[0] = (__bf16)a[0]; r[1] = (__bf16)a[1]; r[2] = (__bf16)a[2]; r[3] = (__bf16)a[3];
  r[4] = (__bf16)b[0]; r[5] = (__bf16)b[1]; r[6] = (__bf16)b[2]; r[7] = (__bf16)b[3];
  return r;
}

// Barrier with LDS-only drain: cross-wave deps are purely LDS; keep global
// loads/stores in flight across the barrier (no vmcnt drain).
__device__ inline void bar_lds() {
  asm volatile("s_waitcnt lgkmcnt(0)" ::: "memory");
  __builtin_amdgcn_s_barrier();
}
}  // namespace

// Prep: VT[b][d][q] = bf16(V[b][q][d]);  QT[b][q][d] = bf16(Q[b][q][d] / 8).
__global__ __launch_bounds__(256)
void prep_kernel(const float* __restrict__ qp, const float* __restrict__ vp,
                 __bf16* __restrict__ qt, __bf16* __restrict__ vt) {
  __shared__ float t[64][65];
  const int tid = threadIdx.x;
  const int b = blockIdx.y;
  const int qb = blockIdx.x * 64;

  {  // V tile -> LDS (f32, padded)
    const int qr = tid >> 4, d0 = (tid & 15) * 4;
#pragma unroll
    for (int p = 0; p < 4; ++p) {
      f32x4 r = *reinterpret_cast<const f32x4*>(
          vp + ((size_t)(b * L + qb + p * 16 + qr)) * D + d0);
      *reinterpret_cast<f32x4*>(&t[p * 16 + qr][d0]) = r;
    }
  }
  {  // Q convert (scaled by 1/8)
    const int qr = tid >> 2, quad = tid & 3;
    const float* src = qp + ((size_t)(b * L + qb + qr)) * D + quad * 16;
    __bf16* dst = qt + (((size_t)(b * L + qb + qr)) << 6) + quad * 16;
#pragma unroll
    for (int h = 0; h < 2; ++h) {
      f32x4 a = *reinterpret_cast<const f32x4*>(src + h * 8);
      f32x4 bb = *reinterpret_cast<const f32x4*>(src + h * 8 + 4);
      a *= 0.125f; bb *= 0.125f;
      bf16x8 r;
#pragma unroll
      for (int j = 0; j < 4; ++j) { r[j] = (__bf16)a[j]; r[4 + j] = (__bf16)bb[j]; }
      *reinterpret_cast<bf16x8*>(dst + h * 8) = r;
    }
  }
  __syncthreads();
  {  // transposed V out: VT rows = d, contiguous q
    const int qh = tid & 7, dr = tid >> 3;
#pragma unroll
    for (int p = 0; p < 2; ++p) {
      const int d = p * 32 + dr;
      bf16x8 r;
#pragma unroll
      for (int j = 0; j < 8; ++j) r[j] = (__bf16)t[qh * 8 + j][d];
      *reinterpret_cast<bf16x8*>(vt + (((size_t)(b * D + d)) << 10) + qb + qh * 8) = r;
    }
  }
}

// Main: block = (batch, 256-k window), 16 waves (1024 thr), full q sweep,
// 256 blocks = 1/CU. Per 32-q step: GEMM1 (each wave owns a 16-k strip) ->
// raw S^T staged in sbuf -> barrier -> cooperative threads (gate/mask held
// in regs from 1KB-contiguous loads) apply sigmoid in coop layout, write
// attn (1KB runs) + P^T bf16 to pbuf -> barrier -> GEMM2 (K=32). Only
// S and P round-trip LDS; gate/mask never touch LDS.
__global__ __launch_bounds__(1024)
void gated_attn_kernel(const __bf16* __restrict__ qt,
                       const float* __restrict__ kp,
                       const __bf16* __restrict__ vt,
                       const int* __restrict__ mask,
                       const float* __restrict__ gate,
                       float* __restrict__ out_o,
                       float* __restrict__ out_attn) {
  __shared__ float sbuf[QS * SP];   // 33.3 KB raw scores S^T as [q][k]
  __shared__ __bf16 pbuf[KT * PP];  // 20.5 KB P^T as [k][q]

  const int tid = threadIdx.x, w = tid >> 6, lane = tid & 63;
  const int c = lane & 15, g = lane >> 4;

  // XCD-grouped decode: all 4 k-blocks of a batch share an XCD (L2 reuse).
  const int i = blockIdx.x;
  const int b = (i & 7) * 8 + (i >> 5);
  const int ktile = ((i >> 3) & 3) * KT;
  const int kw = ktile + w * 16;      // this wave's 16-k strip

  // cooperative coords: 32 rows x 32 threads, 2 x 16B chunks per thread
  const int srow = tid >> 5, scol = (tid & 31) * 4;

  // K fragments (A operand of GEMM1), loop-invariant
  bf16x8 kf[2];
#pragma unroll
  for (int h = 0; h < 2; ++h)
    kf[h] = cvt8(kp + ((size_t)(b * L + kw + c)) * D + h * 32 + g * 8);

  f32x4 acc[4] = {};  // O[k=kw+g*4+j][d=ds*16+c]

  f32x4 sg0, sg1; i32x4 sm0, sm1;  // gate/mask staged in regs (coop layout)
  bf16x8 qf[4];

  auto issue_gm = [&](int q0) {
    const float* gp_ = gate + ((size_t)(b * L + q0 + srow)) * L + ktile + scol;
    sg0 = *reinterpret_cast<const f32x4*>(gp_);
    sg1 = *reinterpret_cast<const f32x4*>(gp_ + 128);
    const int* mp_ = mask + ((size_t)(b * L + q0 + srow)) * L + ktile + scol;
    sm0 = *reinterpret_cast<const i32x4*>(mp_);
    sm1 = *reinterpret_cast<const i32x4*>(mp_ + 128);
  };
  auto load_qf = [&](int q0) {
#pragma unroll
    for (int sub = 0; sub < 2; ++sub) {
      const __bf16* qr = qt + (((size_t)(b * L + q0 + sub * 16 + c)) << 6) + g * 8;
      qf[sub * 2 + 0] = *reinterpret_cast<const bf16x8*>(qr);
      qf[sub * 2 + 1] = *reinterpret_cast<const bf16x8*>(qr + 32);
    }
  };

  issue_gm(0);
  load_qf(0);

  for (int t = 0; t < NSTEP; ++t) {
    const int q0 = t * QS;

    // V^T fragments for this step's GEMM2 (L2-hot; covered by whole step)
    bf16x8 vf[4];
#pragma unroll
    for (int ds = 0; ds < 4; ++ds)
      vf[ds] = *reinterpret_cast<const bf16x8*>(
          vt + (((size_t)(b * D + ds * 16 + c)) << 10) + q0 + g * 8);

    // GEMM1: S^T[16k x 32q] for this wave's strip
    f32x4 s[2];
#pragma unroll
    for (int sub = 0; sub < 2; ++sub) {
      f32x4 cc = {};
      cc = __builtin_amdgcn_mfma_f32_16x16x32_bf16(kf[0], qf[sub * 2 + 0], cc, 0, 0, 0);
      cc = __builtin_amdgcn_mfma_f32_16x16x32_bf16(kf[1], qf[sub * 2 + 1], cc, 0, 0, 0);
      s[sub] = cc;
    }

    // stage raw S^T to sbuf as [q_local][k_local] (b128 stores)
#pragma unroll
    for (int sub = 0; sub < 2; ++sub)
      *reinterpret_cast<f32x4*>(
          &sbuf[(sub * 16 + c) * SP + w * 16 + g * 4]) = s[sub];

    if (t + 1 < NSTEP) load_qf(q0 + QS);  // prefetch next Q (L2-hot)

    bar_lds();  // sbuf visible

    // coop phase: sigmoid in contiguous layout; attn out; P^T -> pbuf
    {
      const f32x4 s0 = *reinterpret_cast<const f32x4*>(&sbuf[srow * SP + scol]);
      const f32x4 s1 = *reinterpret_cast<const f32x4*>(&sbuf[srow * SP + scol + 128]);
      f32x4 p0, p1;
#pragma unroll
      for (int j = 0; j < 4; ++j) {
        const float x0 = s0[j] * sg0[j];
        p0[j] = sm0[j] ? 0.0f : __builtin_amdgcn_rcpf(1.0f + __expf(-x0));
        const float x1 = s1[j] * sg1[j];
        p1[j] = sm1[j] ? 0.0f : __builtin_amdgcn_rcpf(1.0f + __expf(-x1));
      }
      float* op = out_attn + ((size_t)(b * L + q0 + srow)) * L + ktile + scol;
      *reinterpret_cast<f32x4*>(op) = p0;
      *reinterpret_cast<f32x4*>(op + 128) = p1;
#pragma unroll
      for (int j = 0; j < 4; ++j) {
        pbuf[(scol + j) * PP + srow] = (__bf16)p0[j];
        pbuf[(scol + 128 + j) * PP + srow] = (__bf16)p1[j];
      }
    }

    if (t + 1 < NSTEP) issue_gm(q0 + QS);  // next gate/mask (~1 step cover)

    bar_lds();  // pbuf visible

    // GEMM2: O[16k x 64d] += P^T[16k x 32q] * V[32q x 64d]
    const bf16x8 pa =
        *reinterpret_cast<const bf16x8*>(&pbuf[(w * 16 + c) * PP + g * 8]);
#pragma unroll
    for (int ds = 0; ds < 4; ++ds)
      acc[ds] = __builtin_amdgcn_mfma_f32_16x16x32_bf16(pa, vf[ds], acc[ds], 0, 0, 0);
  }

  // epilogue: O direct stores
#pragma unroll
  for (int ds = 0; ds < 4; ++ds)
#pragma unroll
    for (int j = 0; j < 4; ++j)
      out_o[((size_t)(b * L + kw + g * 4 + j)) * D + ds * 16 + c] = acc[ds][j];
}

extern "C" void kernel_launch(void* const* d_in, const int* in_sizes, int n_in,
                              void* d_out, int out_size, void* d_ws, size_t ws_size,
                              hipStream_t stream) {
  const float* q = (const float*)d_in[0];
  const float* k = (const float*)d_in[1];
  const float* v = (const float*)d_in[2];
  const int* mask = (const int*)d_in[3];
  const float* gate = (const float*)d_in[4];

  float* out_o = (float*)d_out;                 // [B, L, D]
  float* out_attn = out_o + (size_t)B * L * D;  // [B, L, L]

  __bf16* qt = (__bf16*)d_ws;                   // [B, L, D] bf16 (scaled 1/8)
  __bf16* vt = qt + (size_t)B * L * D;          // [B, D, L] bf16

  prep_kernel<<<dim3(L / 64, B), dim3(256), 0, stream>>>(q, v, qt, vt);
  gated_attn_kernel<<<dim3(256), dim3(1024), 0, stream>>>(
      qt, k, vt, mask, gate, out_o, out_attn);
}

// Round 10
// 207.265 us; speedup vs baseline: 1.1231x; 1.1231x over previous
//
#include <hip/hip_runtime.h>
#include <hip/hip_bf16.h>

namespace {
constexpr int B = 64, L = 1024, D = 64;
constexpr int KT = 256;        // k-window per block (1KB f32 rows -> contiguity)
constexpr int QS = 16;         // q per step
constexpr int QSPLIT = 2;      // q-range halves -> 512 blocks = 2/CU
constexpr int QRANGE = L / QSPLIT;
constexpr int NSTEP = QRANGE / QS;  // 32
constexpr int GP = 260;        // gate/attn shared-tile pitch (f32 words)
constexpr int MPB = 272;       // mask LDS pitch (bytes)
constexpr int PP = 40;         // P^T LDS pitch (bf16) -> 80B rows, b128-aligned

typedef float f32x4 __attribute__((ext_vector_type(4)));
typedef int   i32x4 __attribute__((ext_vector_type(4)));
typedef __bf16 bf16x8 __attribute__((ext_vector_type(8)));
typedef unsigned int u32;

__device__ inline bf16x8 cvt8(const float* __restrict__ p) {
  f32x4 a = *reinterpret_cast<const f32x4*>(p);
  f32x4 b = *reinterpret_cast<const f32x4*>(p + 4);
  bf16x8 r;
  r[0] = (__bf16)a[0]; r[1] = (__bf16)a[1]; r[2] = (__bf16)a[2]; r[3] = (__bf16)a[3];
  r[4] = (__bf16)b[0]; r[5] = (__bf16)b[1]; r[6] = (__bf16)b[2]; r[7] = (__bf16)b[3];
  return r;
}

// Barrier with LDS-only drain: cross-wave deps are purely LDS; keep global
// loads/stores in flight across the barrier (no vmcnt drain).
__device__ inline void bar_lds() {
  asm volatile("s_waitcnt lgkmcnt(0)" ::: "memory");
  __builtin_amdgcn_s_barrier();
}
}  // namespace

// Prep: VT[b][d][q] = bf16(V[b][q][d]);  QT[b][q][d] = bf16(Q[b][q][d] / 8).
__global__ __launch_bounds__(256)
void prep_kernel(const float* __restrict__ qp, const float* __restrict__ vp,
                 __bf16* __restrict__ qt, __bf16* __restrict__ vt) {
  __shared__ float t[64][65];
  const int tid = threadIdx.x;
  const int b = blockIdx.y;
  const int qb = blockIdx.x * 64;

  {  // V tile -> LDS (f32, padded)
    const int qr = tid >> 4, d0 = (tid & 15) * 4;
#pragma unroll
    for (int p = 0; p < 4; ++p) {
      f32x4 r = *reinterpret_cast<const f32x4*>(
          vp + ((size_t)(b * L + qb + p * 16 + qr)) * D + d0);
      *reinterpret_cast<f32x4*>(&t[p * 16 + qr][d0]) = r;
    }
  }
  {  // Q convert (scaled by 1/8)
    const int qr = tid >> 2, quad = tid & 3;
    const float* src = qp + ((size_t)(b * L + qb + qr)) * D + quad * 16;
    __bf16* dst = qt + (((size_t)(b * L + qb + qr)) << 6) + quad * 16;
#pragma unroll
    for (int h = 0; h < 2; ++h) {
      f32x4 a = *reinterpret_cast<const f32x4*>(src + h * 8);
      f32x4 bb = *reinterpret_cast<const f32x4*>(src + h * 8 + 4);
      a *= 0.125f; bb *= 0.125f;
      bf16x8 r;
#pragma unroll
      for (int j = 0; j < 4; ++j) { r[j] = (__bf16)a[j]; r[4 + j] = (__bf16)bb[j]; }
      *reinterpret_cast<bf16x8*>(dst + h * 8) = r;
    }
  }
  __syncthreads();
  {  // transposed V out: VT rows = d, contiguous q
    const int qh = tid & 7, dr = tid >> 3;
#pragma unroll
    for (int p = 0; p < 2; ++p) {
      const int d = p * 32 + dr;
      bf16x8 r;
#pragma unroll
      for (int j = 0; j < 8; ++j) r[j] = (__bf16)t[qh * 8 + j][d];
      *reinterpret_cast<bf16x8*>(vt + (((size_t)(b * D + d)) << 10) + qb + qh * 8) = r;
    }
  }
}

// Main: block = (batch, 256-k window, 512-q half), 8 waves (512 thr).
// 512 blocks = 2/CU so two blocks' phases interleave on each CU. Per 16-q
// step: cooperative 1KB-contiguous gate/mask loads -> LDS; GEMM1 in frag
// layout; sigmoid from LDS gate/mask; attn written back into the SAME LDS
// tile (each (q,k) word is read-then-written by one thread per phase ->
// the 2 existing barriers cover all cross-thread handoffs); cooperative
// 1KB-contiguous attn writeback; P^T wave-private; GEMM2 (K=32) every 2
// steps. Partial O accumulated with atomicAdd onto memset-zeroed output.
__global__ __launch_bounds__(512)
void gated_attn_kernel(const __bf16* __restrict__ qt,
                       const float* __restrict__ kp,
                       const __bf16* __restrict__ vt,
                       const int* __restrict__ mask,
                       const float* __restrict__ gate,
                       float* __restrict__ out_o,
                       float* __restrict__ out_attn) {
  __shared__ float gbuf[QS * GP];           // 16.6 KB gate tile / attn tile
  __shared__ unsigned char mbuf[QS * MPB];  //  4.3 KB mask bytes
  __shared__ __bf16 pbuf[KT * PP];          // 20.5 KB P^T (wave-private rows)

  const int tid = threadIdx.x, w = tid >> 6, lane = tid & 63;
  const int c = lane & 15, g = lane >> 4;

  // Decode: 8 blocks of a batch (4 ktiles x 2 qhalves) share an XCD.
  const int i = blockIdx.x;
  const int xcd = i & 7, slot = i >> 3;
  const int b = xcd * 8 + (slot & 7);
  const int cfg = slot >> 3;                 // 0..7
  const int ktile = (cfg & 3) * KT;
  const int qbase = (cfg >> 2) * QRANGE;
  const int kw = ktile + w * 32;

  // cooperative staging coords: 32 threads/row, 2 chunks of 16B per thread
  const int srow = tid >> 5, scol = (tid & 31) * 4;

  // K fragments (A operand of GEMM1), loop-invariant
  bf16x8 kf[2][2];
#pragma unroll
  for (int ks = 0; ks < 2; ++ks)
#pragma unroll
    for (int h = 0; h < 2; ++h)
      kf[ks][h] = cvt8(kp + ((size_t)(b * L + kw + ks * 16 + c)) * D + h * 32 + g * 8);

  f32x4 acc[2][4] = {};  // O[k=kw+ks*16+g*4+j][d=ds*16+c]

  f32x4 sg0, sg1; i32x4 sm0, sm1;  // staged gate/mask regs (1-step pipeline)
  bf16x8 qf0, qf1;

  auto issue_gm = [&](int q0) {
    const float* gp_ = gate + ((size_t)(b * L + q0 + srow)) * L + ktile + scol;
    sg0 = *reinterpret_cast<const f32x4*>(gp_);
    sg1 = *reinterpret_cast<const f32x4*>(gp_ + 128);
    const int* mp_ = mask + ((size_t)(b * L + q0 + srow)) * L + ktile + scol;
    sm0 = *reinterpret_cast<const i32x4*>(mp_);
    sm1 = *reinterpret_cast<const i32x4*>(mp_ + 128);
  };
  auto write_gm = [&]() {
    *reinterpret_cast<f32x4*>(&gbuf[srow * GP + scol]) = sg0;
    *reinterpret_cast<f32x4*>(&gbuf[srow * GP + scol + 128]) = sg1;
    const u32 p0 = (u32)(sm0[0] & 1) | ((u32)(sm0[1] & 1) << 8) |
                   ((u32)(sm0[2] & 1) << 16) | ((u32)(sm0[3] & 1) << 24);
    const u32 p1 = (u32)(sm1[0] & 1) | ((u32)(sm1[1] & 1) << 8) |
                   ((u32)(sm1[2] & 1) << 16) | ((u32)(sm1[3] & 1) << 24);
    *reinterpret_cast<u32*>(&mbuf[srow * MPB + scol]) = p0;
    *reinterpret_cast<u32*>(&mbuf[srow * MPB + scol + 128]) = p1;
  };
  auto load_qf = [&](int q0) {
    const __bf16* qr = qt + (((size_t)(b * L + q0 + c)) << 6) + g * 8;
    qf0 = *reinterpret_cast<const bf16x8*>(qr);
    qf1 = *reinterpret_cast<const bf16x8*>(qr + 32);
  };

  // prologue: tile 0 into LDS, tile 1 into regs
  issue_gm(qbase);
  write_gm();
  issue_gm(qbase + QS);
  load_qf(qbase);
  __syncthreads();

  for (int t = 0; t < NSTEP; ++t) {
    const int par = t & 1, q0 = qbase + t * QS;

    // GEMM1: S^T[32k_w x 16q]
    f32x4 s[2];
#pragma unroll
    for (int ks = 0; ks < 2; ++ks) {
      f32x4 cc = {};
      cc = __builtin_amdgcn_mfma_f32_16x16x32_bf16(kf[ks][0], qf0, cc, 0, 0, 0);
      cc = __builtin_amdgcn_mfma_f32_16x16x32_bf16(kf[ks][1], qf1, cc, 0, 0, 0);
      s[ks] = cc;
    }
    if (t + 1 < NSTEP) load_qf(q0 + QS);  // prefetch next Q (L2-hot)

    // elementwise from LDS gate/mask; attn back into gbuf (same word, same
    // thread); P^T -> pbuf
#pragma unroll
    for (int ks = 0; ks < 2; ++ks) {
      const int kl = w * 32 + ks * 16 + g * 4;
      const f32x4 gv = *reinterpret_cast<const f32x4*>(&gbuf[c * GP + kl]);
      const u32 mv = *reinterpret_cast<const u32*>(&mbuf[c * MPB + kl]);
      f32x4 p;
#pragma unroll
      for (int j = 0; j < 4; ++j) {
        const float x = s[ks][j] * gv[j];
        const float e = __expf(-x);
        p[j] = ((mv >> (8 * j)) & 0xffu) ? 0.0f : __builtin_amdgcn_rcpf(1.0f + e);
      }
      *reinterpret_cast<f32x4*>(&gbuf[c * GP + kl]) = p;
#pragma unroll
      for (int j = 0; j < 4; ++j)
        pbuf[(kl + j) * PP + par * 16 + c] = (__bf16)p[j];
    }

    bar_lds();  // attn (in gbuf) + P visible; all gate/mask reads done

    // GEMM2 every q-pair (K=32); pbuf rows are this wave's own writes
    if (par == 1) {
      const int qp0 = qbase + (t >> 1) * 32;
#pragma unroll
      for (int ks = 0; ks < 2; ++ks) {
        const bf16x8 pa = *reinterpret_cast<const bf16x8*>(
            &pbuf[(w * 32 + ks * 16 + c) * PP + g * 8]);
#pragma unroll
        for (int ds = 0; ds < 4; ++ds) {
          const bf16x8 vf = *reinterpret_cast<const bf16x8*>(
              vt + (((size_t)(b * D + ds * 16 + c)) << 10) + qp0 + g * 8);
          acc[ks][ds] =
              __builtin_amdgcn_mfma_f32_16x16x32_bf16(pa, vf, acc[ks][ds], 0, 0, 0);
        }
      }
    }

    // cooperative contiguous attn writeback (1KB runs), then overwrite the
    // same words with next step's gate (same thread -> no barrier needed)
    {
      const f32x4 a0 = *reinterpret_cast<const f32x4*>(&gbuf[srow * GP + scol]);
      const f32x4 a1 = *reinterpret_cast<const f32x4*>(&gbuf[srow * GP + scol + 128]);
      float* op = out_attn + ((size_t)(b * L + q0 + srow)) * L + ktile + scol;
      *reinterpret_cast<f32x4*>(op) = a0;
      *reinterpret_cast<f32x4*>(op + 128) = a1;
    }

    // commit staged regs (t+1) to LDS; issue loads for t+2
    write_gm();
    if (t + 2 < NSTEP) issue_gm(q0 + 2 * QS);

    bar_lds();  // staged tile visible for step t+1 (LDS-only deps)
  }

  // epilogue: partial-O accumulate (out_o zeroed by memset; 2-way atomics)
#pragma unroll
  for (int ks = 0; ks < 2; ++ks)
#pragma unroll
    for (int ds = 0; ds < 4; ++ds)
#pragma unroll
      for (int j = 0; j < 4; ++j)
        atomicAdd(&out_o[((size_t)(b * L + kw + ks * 16 + g * 4 + j)) * D +
                         ds * 16 + c],
                  acc[ks][ds][j]);
}

extern "C" void kernel_launch(void* const* d_in, const int* in_sizes, int n_in,
                              void* d_out, int out_size, void* d_ws, size_t ws_size,
                              hipStream_t stream) {
  const float* q = (const float*)d_in[0];
  const float* k = (const float*)d_in[1];
  const float* v = (const float*)d_in[2];
  const int* mask = (const int*)d_in[3];
  const float* gate = (const float*)d_in[4];

  float* out_o = (float*)d_out;                 // [B, L, D]
  float* out_attn = out_o + (size_t)B * L * D;  // [B, L, L]

  __bf16* qt = (__bf16*)d_ws;                   // [B, L, D] bf16 (scaled 1/8)
  __bf16* vt = qt + (size_t)B * L * D;          // [B, D, L] bf16

  hipMemsetAsync(out_o, 0, (size_t)B * L * D * sizeof(float), stream);
  prep_kernel<<<dim3(L / 64, B), dim3(256), 0, stream>>>(q, v, qt, vt);
  gated_attn_kernel<<<dim3(256 * QSPLIT), dim3(512), 0, stream>>>(
      qt, k, vt, mask, gate, out_o, out_attn);
}